// Round 15
// baseline (154.880 us; speedup 1.0000x reference)
//
#include <hip/hip_runtime.h>
#include <math.h>

// MemoryCenters: sim = q·K^T (1024x100000, D=128), top-32 by rbf=exp(-2*dist_sq),
// softmax(log(rbf+eps)+log(h+eps)), r_V = w·V_sel, r_E = w·e_sel.
//
// Round 15 = Round 14's wide-A tile (128q x 64c, 4 waves of 64q x 32c,
// af[4][4]: 4 MFMA per ds_read — the VALU/MFMA win) with the R14 occupancy
// regression fixed: R14's grid (128,8)=1024 blocks = exactly ONE residency
// round (4 blk/CU x 256 CU) -> Occupancy 37->21%. Now NGRP 128->256 center
// groups (6-7 tiles each) -> grid (256,8)=2048 blocks = 2 rounds (R12 regime).
// BCAP 12 kept safe by sharpening the threshold: u8 bins over [-0.5,0.5]
// (2x finer; 32nd sim ~0.25 well inside) -> slop 0.028->0.020 -> ~520
// survivors/query, lambda~2.0/bucket, P(overflow anywhere)~5e-2 expected 0.05.
// buckets = 1024x256x12x4B = 12.58MB = binsU8 alias; cnt2 1MB; ws ~39.4MB.
// finalize: 256-group scan (4-wave hierarchical). Key quantization unchanged.
// convert/thresh structure identical; gemm loop identical to R14.

#define DDIM    128
#define MSAMPLE 12288
#define NBINS   256
#define TOPK    32
#define NQTOT   1024
#define NGRP    256
#define BCAP    12
#define EPSM    0.012f
#define SORTN   1024
#define FINEN   256
#define QSH     17
#define QMASK   0x1FFFFu
#define QMARGIN 200u      // 200/16384 = 0.0122 >= 2*EA(0.004) + 2 quanta

typedef __attribute__((ext_vector_type(8))) short short8;   // 8 bf16 = 4 VGPRs
typedef __attribute__((ext_vector_type(4))) float f32x4;    // mfma C/D frag

__device__ inline unsigned short f2bf(float f) {
    unsigned u = __builtin_bit_cast(unsigned, f);
    return (unsigned short)((u + 0x7FFFu + ((u >> 16) & 1u)) >> 16);
}

// ---------------------------------------------------------------------------
__global__ __launch_bounds__(256)
void convert_kernel(const float* __restrict__ Qg, const float* __restrict__ Kg,
                    unsigned short* __restrict__ Qbf, unsigned short* __restrict__ Kbf,
                    int nq8, int nk8)
{
    int total = nq8 + nk8;
    for (int i = blockIdx.x * 256 + threadIdx.x; i < total; i += gridDim.x * 256) {
        const float* s; unsigned short* d; int j;
        if (i < nq8) { s = Qg; d = Qbf; j = i; }
        else         { s = Kg; d = Kbf; j = i - nq8; }
        float4 a = *reinterpret_cast<const float4*>(s + (size_t)j * 8);
        float4 b = *reinterpret_cast<const float4*>(s + (size_t)j * 8 + 4);
        short8 o;
        o[0] = (short)f2bf(a.x); o[1] = (short)f2bf(a.y);
        o[2] = (short)f2bf(a.z); o[3] = (short)f2bf(a.w);
        o[4] = (short)f2bf(b.x); o[5] = (short)f2bf(b.y);
        o[6] = (short)f2bf(b.z); o[7] = (short)f2bf(b.w);
        *reinterpret_cast<short8*>(d + (size_t)j * 8) = o;
    }
}

// ---------------------------------------------------------------------------
// bf16 MFMA GEMM, 128q x 64c tile, 4 waves (2 row x 2 col; wave = 64q x 32c),
// A in registers (af[4][4]), B double-buffered (2x16KB) via global_load_lds
// (pre-swizzled src cc^(r&15), linear LDS dest, swizzled read), per-row
// thresholds in LDS. MODE 0: u8 bins ([-0.5,0.5] range). MODE 1: bucket-append.
// ---------------------------------------------------------------------------
template<int MODE>
__global__ __launch_bounds__(256)
void gemm_pass(const unsigned short* __restrict__ Qb, const unsigned short* __restrict__ Kb,
               int N, unsigned char* __restrict__ binsU8,
               const float* __restrict__ thr,
               int* __restrict__ cnt2, unsigned int* __restrict__ buckets)
{
    __shared__ __align__(16) unsigned char Bs[2][64 * 256];  // 2 x 16KB
    __shared__ int off_l[128];
    __shared__ float thr_l[128];
    const int tid   = threadIdx.x;
    const int lane  = tid & 63;
    const int w     = tid >> 6;           // 0..3
    const int wr    = (w >> 1) * 64;      // 2 row blocks of 64 q
    const int wc    = (w & 1) * 32;       // 2 col blocks of 32 c
    const int lr    = lane & 15;
    const int lk    = lane >> 4;          // 0..3
    const int g     = blockIdx.x;
    const int qbase = blockIdx.y * 128;

    int t0, tcnt;
    if (MODE == 0) { t0 = g; tcnt = 1; }                      // 192 sample tiles
    else { t0 = g * 6 + min(g, 27); tcnt = 6 + (g < 27 ? 1 : 0); }  // 1563 tiles

    if (MODE == 1) {
        for (int i = tid; i < 128; i += 256) {
            off_l[i] = 0;
            thr_l[i] = thr[qbase + i] - EPSM;
        }
    }

#define STAGE(buf, tile) do {                                                  \
    const int cbase_ = (tile) * 64;                                            \
    _Pragma("unroll")                                                          \
    for (int it = 0; it < 4; ++it) {                                           \
        int flat = it * 256 + tid;                                             \
        int r_ = flat >> 4, cc_ = flat & 15;                                   \
        int row_ = cbase_ + r_;                                                \
        if (MODE == 1 && row_ >= N) row_ = N - 1;  /* epilogue c<N discards */ \
        const unsigned short* src_ = Kb + (size_t)row_ * DDIM                  \
                                        + ((cc_ ^ (r_ & 15)) * 8);             \
        unsigned char* dst_ = &Bs[buf][(size_t)(it * 256 + (tid & ~63)) * 16]; \
        __builtin_amdgcn_global_load_lds(                                      \
            (const __attribute__((address_space(1))) unsigned int*)src_,       \
            (__attribute__((address_space(3))) unsigned int*)dst_, 16, 0, 0);  \
    }                                                                          \
} while (0)

    // ---- A fragments in registers: af[fm][ks] = 16 short8 = 64 VGPR ----
    short8 af[4][4];
    #pragma unroll
    for (int fm = 0; fm < 4; ++fm)
        #pragma unroll
        for (int ks = 0; ks < 4; ++ks)
            af[fm][ks] = *reinterpret_cast<const short8*>(
                Qb + (size_t)(qbase + wr + fm * 16 + lr) * DDIM + (ks * 4 + lk) * 8);

    STAGE(0, t0);
    __syncthreads();
    int cur = 0;

    for (int t = 0; t < tcnt; ++t) {
        if (t + 1 < tcnt) STAGE(cur ^ 1, t0 + t + 1);   // in flight under compute

        const int cbase = (t0 + t) * 64;
        const unsigned char* bsc = Bs[cur];

        const f32x4 z = {0.f, 0.f, 0.f, 0.f};
        f32x4 acc[4][2];
        #pragma unroll
        for (int a = 0; a < 4; ++a)
            #pragma unroll
            for (int b = 0; b < 2; ++b) acc[a][b] = z;

        #pragma unroll
        for (int ks = 0; ks < 4; ++ks) {
            short8 bg[2];
            #pragma unroll
            for (int fn = 0; fn < 2; ++fn) {
                int rb = wc + fn * 16 + lr;
                bg[fn] = *reinterpret_cast<const short8*>(
                    bsc + rb * 256 + (((ks * 4 + lk) ^ (rb & 15)) << 4));
            }
            #pragma unroll
            for (int fm = 0; fm < 4; ++fm)
                #pragma unroll
                for (int fn = 0; fn < 2; ++fn)
                    acc[fm][fn] = __builtin_amdgcn_mfma_f32_16x16x32_bf16(
                        af[fm][ks], bg[fn], acc[fm][fn], 0, 0, 0);
        }

        // epilogue — C/D map: col = lane&15, row = (lane>>4)*4 + reg [m89/m91]
        #pragma unroll
        for (int fm = 0; fm < 4; ++fm) {
            #pragma unroll
            for (int j = 0; j < 4; ++j) {
                const int ql = wr + fm * 16 + lk * 4 + j;
                if (MODE == 0) {
                    #pragma unroll
                    for (int fn = 0; fn < 2; ++fn) {
                        const int c = cbase + wc + fn * 16 + lr;
                        float s = acc[fm][fn][j];
                        // u8 bins over [-0.5, 0.5], width 1/256
                        int b = (int)((s + 0.5f) * 256.0f);
                        b = b < 0 ? 0 : (b > NBINS - 1 ? NBINS - 1 : b);
                        binsU8[(size_t)(qbase + ql) * MSAMPLE + c] = (unsigned char)b;
                    }
                } else {
                    const float t_ = thr_l[ql];
                    const float s0 = acc[fm][0][j], s1 = acc[fm][1][j];
                    if (__any(fmaxf(s0, s1) >= t_)) {
                        #pragma unroll
                        for (int fn = 0; fn < 2; ++fn) {
                            const int c = cbase + wc + fn * 16 + lr;
                            const float s = fn ? s1 : s0;
                            if (c < N && s >= t_) {
                                int qs = (int)((s + 1.0f) * 16384.0f);
                                qs = qs < 0 ? 0 : (qs > 32767 ? 32767 : qs);
                                unsigned key = ((unsigned)qs << QSH)
                                             | (~(unsigned)c & QMASK);
                                int p = atomicAdd(&off_l[ql], 1);   // LDS-local
                                if (p < BCAP)
                                    buckets[((size_t)(qbase + ql) * NGRP + g) * BCAP + p] = key;
                            }
                        }
                    }
                }
            }
        }
        __syncthreads();
        cur ^= 1;
    }
#undef STAGE

    if (MODE == 1) {
        for (int i = tid; i < 128; i += 256)
            cnt2[(qbase + i) * NGRP + g] = min(off_l[i], BCAP);
    }
}

// ---------------------------------------------------------------------------
// thresh with per-wave sub-histograms; bins over [-0.5,0.5]
// ---------------------------------------------------------------------------
__global__ __launch_bounds__(256)
void thresh_kernel(const unsigned char* __restrict__ bins, float* __restrict__ thr)
{
    __shared__ int hS[4 * NBINS];
    __shared__ int hA[NBINS];
    __shared__ int hB[NBINS];
    __shared__ int best;
    const int q = blockIdx.x, tid = threadIdx.x;
    const int wv = tid >> 6;
    for (int i = tid; i < 4 * NBINS; i += 256) hS[i] = 0;
    if (tid == 0) best = 0;
    __syncthreads();
    const uint4* bp = reinterpret_cast<const uint4*>(bins + (size_t)q * MSAMPLE);
    int* hw = hS + wv * NBINS;
    for (int i = tid; i < MSAMPLE / 16; i += 256) {
        uint4 v = bp[i];
        unsigned xs[4] = {v.x, v.y, v.z, v.w};
        #pragma unroll
        for (int k = 0; k < 4; ++k) {
            unsigned x = xs[k];
            atomicAdd(&hw[x & 255], 1); x >>= 8;
            atomicAdd(&hw[x & 255], 1); x >>= 8;
            atomicAdd(&hw[x & 255], 1); x >>= 8;
            atomicAdd(&hw[x & 255], 1);
        }
    }
    __syncthreads();
    for (int i = tid; i < NBINS; i += 256)
        hA[i] = hS[i] + hS[NBINS + i] + hS[2 * NBINS + i] + hS[3 * NBINS + i];
    __syncthreads();
    int* src = hA; int* dst = hB;
    for (int off = 1; off < NBINS; off <<= 1) {
        for (int i = tid; i < NBINS; i += 256)
            dst[i] = src[i] + ((i + off < NBINS) ? src[i + off] : 0);
        __syncthreads();
        int* tmp = src; src = dst; dst = tmp;
    }
    for (int i = tid; i < NBINS; i += 256)
        if (src[i] >= TOPK) atomicMax(&best, i);
    __syncthreads();
    if (tid == 0)
        thr[q] = (float)(best - 1) * (1.0f / 256.0f) - 0.5f;   // lower edge - 1 bin
}

// ---------------------------------------------------------------------------
// Finalize: compact unsorted (256 groups, 4-wave hierarchical scan) ->
// 256-bin histogram rank-selection -> exact fp32 rbf for head set ->
// 256-wide u64 bitonic (rbf desc, idx asc = jax.lax.top_k) -> weights, gathers.
// ---------------------------------------------------------------------------
__global__ __launch_bounds__(256)
void finalize_kernel(const unsigned int* __restrict__ buckets, const int* __restrict__ cnt2,
                     const float* __restrict__ Qg, const float* __restrict__ Kg,
                     const float* __restrict__ V, const float* __restrict__ hIn,
                     const float* __restrict__ eIn,
                     float* __restrict__ out, int N)
{
    __shared__ float qv[DDIM];
    __shared__ unsigned sk[SORTN];
    __shared__ unsigned fk[FINEN];
    __shared__ unsigned long long sk64[FINEN];
    __shared__ int hA[NBINS];
    __shared__ int hB[NBINS];
    __shared__ int cnts[NGRP], offs[NGRP];
    __shared__ int wpart[4];
    __shared__ int bestb, nsel;
    __shared__ float selV[TOPK];
    __shared__ int   selI[TOPK];
    __shared__ float wts[TOPK];
    const int q = blockIdx.x, tid = threadIdx.x;

    if (tid < DDIM) qv[tid] = Qg[(size_t)q * DDIM + tid];
    cnts[tid] = cnt2[q * NGRP + tid];                 // NGRP == blockDim == 256
    for (int i = tid; i < SORTN; i += 256) sk[i] = 0u;
    if (tid < NBINS) hA[tid] = 0;
    if (tid < FINEN) sk64[tid] = 0ull;
    if (tid == 0) { bestb = 0; nsel = 0; }
    __syncthreads();
    // 256-wide scan: per-wave (64) inclusive shfl scan + wave partial offsets
    int cv = cnts[tid];
    int xv = cv;
    #pragma unroll
    for (int o = 1; o < 64; o <<= 1) {
        int y = __shfl_up(xv, o);
        if ((tid & 63) >= o) xv += y;
    }
    if ((tid & 63) == 63) wpart[tid >> 6] = xv;
    __syncthreads();
    {
        int add = 0;
        const int myw = tid >> 6;
        #pragma unroll
        for (int ww = 0; ww < 4; ++ww)
            if (ww < myw) add += wpart[ww];
        offs[tid] = xv - cv + add;
    }
    __syncthreads();
    for (int flat = tid; flat < NGRP * BCAP; flat += 256) {
        int gg = flat / BCAP, j = flat - gg * BCAP;
        if (j < cnts[gg]) {
            int dst = offs[gg] + j;
            if (dst < SORTN)
                sk[dst] = buckets[((size_t)q * NGRP + gg) * BCAP + j];
        }
    }
    __syncthreads();
    for (int i = tid; i < SORTN; i += 256) {
        unsigned k = sk[i];
        if (k) atomicAdd(&hA[k >> 24], 1);
    }
    __syncthreads();
    {
        int* src = hA; int* dst = hB;
        for (int off = 1; off < NBINS; off <<= 1) {
            for (int i = tid; i < NBINS; i += 256)
                dst[i] = src[i] + ((i + off < NBINS) ? src[i + off] : 0);
            __syncthreads();
            int* tmp = src; src = dst; dst = tmp;
        }
        for (int i = tid; i < NBINS; i += 256)
            if (src[i] >= TOPK) atomicMax(&bestb, i);
    }
    __syncthreads();
    const unsigned b32q = (unsigned)bestb << 7;
    const unsigned cutq = b32q > QMARGIN ? b32q - QMARGIN : 0u;
    const unsigned cutKey = cutq << QSH;
    for (int i = tid; i < SORTN; i += 256) {
        unsigned k = sk[i];
        if (k != 0u && k >= cutKey) {
            int p = atomicAdd(&nsel, 1);
            if (p < FINEN) fk[p] = k;
        }
    }
    __syncthreads();
    const int m = min(nsel, FINEN);
    const int sub = tid & 3, ci = tid >> 2;
    #pragma unroll
    for (int base = 0; base < FINEN; base += 64) {
        int i = base + ci;
        bool act = i < m;
        int c = 0;
        float s = 0.f;
        if (act) {
            c = (int)(~fk[i] & QMASK);
            const float4* k4 = reinterpret_cast<const float4*>(Kg + (size_t)c * DDIM) + sub;
            const float4* q4 = reinterpret_cast<const float4*>(qv) + sub;
            #pragma unroll
            for (int d = 0; d < 8; ++d) {
                float4 kk = k4[d * 4];
                float4 qq = q4[d * 4];
                s = fmaf(qq.x, kk.x, s); s = fmaf(qq.y, kk.y, s);
                s = fmaf(qq.z, kk.z, s); s = fmaf(qq.w, kk.w, s);
            }
        }
        s += __shfl_xor(s, 1); s += __shfl_xor(s, 2);
        if (act && sub == 0) {
            float dist = 2.0f - 2.0f * s;              // reference op order
            float rbf = expf(dist * -2.0f);            // exp(-dist/(2*0.25))
            sk64[i] = ((unsigned long long)__float_as_uint(rbf) << 32)
                    | (unsigned)(~(unsigned)c);        // rbf desc, then idx asc
        }
    }
    __syncthreads();
    for (int k = 2; k <= FINEN; k <<= 1) {
        for (int j = k >> 1; j > 0; j >>= 1) {
            int x = tid ^ j;
            if (x > tid) {
                unsigned long long a = sk64[tid], b = sk64[x];
                bool sw = ((tid & k) == 0) ? (a < b) : (a > b);
                if (sw) { sk64[tid] = b; sk64[x] = a; }
            }
            __syncthreads();
        }
    }
    if (tid < TOPK) {
        unsigned long long kk = sk64[tid];
        float rbf = __uint_as_float((unsigned)(kk >> 32));
        int   idx = (int)(~(unsigned)kk);
        selV[tid] = rbf; selI[tid] = idx;
        float lw = logf(rbf + 1e-8f) + logf(hIn[idx] + 1e-8f);
        float mx = lw;
        #pragma unroll
        for (int o = 16; o > 0; o >>= 1) mx = fmaxf(mx, __shfl_xor(mx, o));
        float ex = expf(lw - mx);
        float sm = ex;
        #pragma unroll
        for (int o = 16; o > 0; o >>= 1) sm += __shfl_xor(sm, o);
        wts[tid] = ex / sm;
    }
    __syncthreads();
    {
        float acc = 0.f;
        const int v = tid;
        #pragma unroll
        for (int k = 0; k < TOPK; ++k)
            acc = fmaf(wts[k], V[(size_t)selI[k] * 256 + v], acc);
        out[(size_t)q * 256 + v] = acc;
    }
    const int offE = NQTOT * 256;
    const int offW = offE + NQTOT * 4;
    const int offI = offW + NQTOT * TOPK;
    if (tid < 4) {
        float acc = 0.f;
        #pragma unroll
        for (int k = 0; k < TOPK; ++k)
            acc = fmaf(wts[k], eIn[(size_t)selI[k] * 4 + tid], acc);
        out[offE + q * 4 + tid] = acc;
    }
    if (tid < TOPK) {
        out[offW + q * TOPK + tid] = wts[tid];
        out[offI + q * TOPK + tid] = (float)selI[tid];
    }
}

// ---------------------------------------------------------------------------
extern "C" void kernel_launch(void* const* d_in, const int* in_sizes, int n_in,
                              void* d_out, int out_size, void* d_ws, size_t ws_size,
                              hipStream_t stream)
{
    (void)n_in; (void)out_size; (void)ws_size;
    const float* Qg = (const float*)d_in[0];
    const float* Kg = (const float*)d_in[1];
    const float* Vg = (const float*)d_in[2];
    const float* hg = (const float*)d_in[3];
    const float* eg = (const float*)d_in[4];
    const int N = in_sizes[1] / DDIM;          // 100000

    char* w = (char*)d_ws;
    unsigned short* Kbf = (unsigned short*)w;  w += (size_t)N * DDIM * 2;      // 25.6MB
    unsigned short* Qbf = (unsigned short*)w;  w += (size_t)NQTOT * DDIM * 2;  // 256KB
    float* thr = (float*)w;                    w += NQTOT * 4;                 // 4KB
    int*   cnt2 = (int*)w;                     w += (size_t)NQTOT * NGRP * 4;  // 1MB
    unsigned char* binsU8 = (unsigned char*)w;                                 // 12.58MB
    unsigned int*  buckets = (unsigned int*)w; // aliases binsU8 (12.58MB, sequential lifetimes)

    hipMemsetAsync(cnt2, 0, (size_t)NQTOT * NGRP * 4, stream);

    dim3 blk(256);
    convert_kernel<<<dim3(2048), blk, 0, stream>>>(
        Qg, Kg, Qbf, Kbf, NQTOT * DDIM / 8, N * DDIM / 8);
    gemm_pass<0><<<dim3(MSAMPLE / 64, NQTOT / 128), blk, 0, stream>>>(
        Qbf, Kbf, N, binsU8, nullptr, nullptr, nullptr);
    thresh_kernel<<<dim3(NQTOT), blk, 0, stream>>>(binsU8, thr);
    gemm_pass<1><<<dim3(NGRP, NQTOT / 128), blk, 0, stream>>>(
        Qbf, Kbf, N, nullptr, thr, cnt2, buckets);
    finalize_kernel<<<dim3(NQTOT), blk, 0, stream>>>(
        buckets, cnt2, Qg, Kg, Vg, hg, eg, (float*)d_out, N);
}

// Round 16
// 131.538 us; speedup vs baseline: 1.1775x; 1.1775x over previous
//
#include <hip/hip_runtime.h>
#include <math.h>

// MemoryCenters: sim = q·K^T (1024x100000, D=128), top-32 by rbf=exp(-2*dist_sq),
// softmax(log(rbf+eps)+log(h+eps)), r_V = w·V_sel, r_E = w·e_sel.
//
// Round 16 = Round 12 (best: 131us; pass-2 67.8us, VALU 44% @ 3 waves/SIMD =
// issue-starved) with the GEMM's LDS halved to double resident waves:
//   B staged in HALF-K chunks: buffer = 64 rows x 64 dims = 8KB; 2 buffers +
//   off_l ~= 16.9KB -> 8 blocks/CU (32 waves, wave-slot cap) vs R12's 3.
//   Same 64qx64c tile, af[2][4], acc[2][2], VGPR 60 (<=64 keeps 8 waves/SIMD).
//   Two half-steps per K-tile: ks-chunk map (ksl*4+lk)^(r&7) per half ->
//   bitwise-identical sims to R12 -> identical survivor set. R12's proven
//   2-phase stage-ahead + __syncthreads per half (R13 showed counted-vmcnt
//   loses to occupancy; drains overlap across 8 blocks).
// convert/thresh/finalize byte-identical to R12 (131us run).
// ws: 25.6MB Kbf + 256KB Qbf + 4KB thr + 512KB cnt2 + 12.58MB (binsU8|buckets).

#define DDIM    128
#define MSAMPLE 12288
#define NBINS   256
#define TOPK    32
#define NQTOT   1024
#define NGRP    128
#define BCAP    24
#define EPSM    0.012f
#define SORTN   1024
#define FINEN   256
#define QSH     17
#define QMASK   0x1FFFFu
#define QMARGIN 200u      // 200/16384 = 0.0122 >= 2*EA(0.004) + 2 quanta

typedef __attribute__((ext_vector_type(8))) short short8;   // 8 bf16 = 4 VGPRs
typedef __attribute__((ext_vector_type(4))) float f32x4;    // mfma C/D frag

__device__ inline unsigned short f2bf(float f) {
    unsigned u = __builtin_bit_cast(unsigned, f);
    return (unsigned short)((u + 0x7FFFu + ((u >> 16) & 1u)) >> 16);
}

// ---------------------------------------------------------------------------
__global__ __launch_bounds__(256)
void convert_kernel(const float* __restrict__ Qg, const float* __restrict__ Kg,
                    unsigned short* __restrict__ Qbf, unsigned short* __restrict__ Kbf,
                    int nq8, int nk8)
{
    int total = nq8 + nk8;
    for (int i = blockIdx.x * 256 + threadIdx.x; i < total; i += gridDim.x * 256) {
        const float* s; unsigned short* d; int j;
        if (i < nq8) { s = Qg; d = Qbf; j = i; }
        else         { s = Kg; d = Kbf; j = i - nq8; }
        float4 a = *reinterpret_cast<const float4*>(s + (size_t)j * 8);
        float4 b = *reinterpret_cast<const float4*>(s + (size_t)j * 8 + 4);
        short8 o;
        o[0] = (short)f2bf(a.x); o[1] = (short)f2bf(a.y);
        o[2] = (short)f2bf(a.z); o[3] = (short)f2bf(a.w);
        o[4] = (short)f2bf(b.x); o[5] = (short)f2bf(b.y);
        o[6] = (short)f2bf(b.z); o[7] = (short)f2bf(b.w);
        *reinterpret_cast<short8*>(d + (size_t)j * 8) = o;
    }
}

// ---------------------------------------------------------------------------
// bf16 MFMA GEMM, 64x64 tile, 4 waves (2x2; wave = 32q x 32c), A in registers
// (af[2][4]), B staged in HALF-K 8KB buffers (2x8KB) via global_load_lds
// (pre-swizzled src (ksl*4+lk)^(r&7) within each 128B half-row, linear LDS
// dest, swizzled read). 16.9KB LDS -> 8 blocks/CU = 32 waves/CU.
// MODE 0: u8 bins over [-1,1]. MODE 1: bucket-append packed keys.
// ---------------------------------------------------------------------------
template<int MODE>
__global__ __launch_bounds__(256)
void gemm_pass(const unsigned short* __restrict__ Qb, const unsigned short* __restrict__ Kb,
               int N, unsigned char* __restrict__ binsU8,
               const float* __restrict__ thr,
               int* __restrict__ cnt2, unsigned int* __restrict__ buckets)
{
    __shared__ __align__(16) unsigned char Bs[2][64 * 128];  // 2 x 8KB (half-K)
    __shared__ int off_l[64];
    const int tid   = threadIdx.x;
    const int lane  = tid & 63;
    const int w     = tid >> 6;           // 0..3
    const int wr    = (w >> 1) * 32;      // 2 row blocks of 32 q
    const int wc    = (w & 1) * 32;       // 2 col blocks of 32 c
    const int lr    = lane & 15;
    const int lk    = lane >> 4;          // 0..3
    const int g     = blockIdx.x;
    const int qbase = blockIdx.y * 64;

    int t0, tcnt;
    if (MODE == 0) { t0 = g; tcnt = 1; }                      // 192 sample tiles
    else { t0 = g * 12 + min(g, 27); tcnt = 12 + (g < 27 ? 1 : 0); }  // 1563 tiles

    if (MODE == 1)
        for (int i = tid; i < 64; i += 256) off_l[i] = 0;

// stage HALF of tile's B (64 rows x 64 dims = 8KB) into Bs[buf]:
// linear LDS dest (wave-uniform base + lane*16), global source pre-swizzled
// within the 128B half-row (chunk cc ^ (r&7)), so swizzled reads see chunk
// (ksl*4+lk) at row rb.
#define STAGE(buf, tile, half) do {                                            \
    const int cbase_ = (tile) * 64;                                            \
    _Pragma("unroll")                                                          \
    for (int it = 0; it < 2; ++it) {                                           \
        int flat = it * 256 + tid;          /* 0..511 */                       \
        int r_ = flat >> 3, cc_ = flat & 7; /* row 0..63, chunk 0..7 */        \
        int row_ = cbase_ + r_;                                                \
        if (MODE == 1 && row_ >= N) row_ = N - 1;  /* epilogue c<N discards */ \
        const unsigned short* src_ = Kb + (size_t)row_ * DDIM + (half) * 64    \
                                        + ((cc_ ^ (r_ & 7)) * 8);              \
        unsigned char* dst_ = &Bs[buf][(size_t)(it * 256 + (tid & ~63)) * 16]; \
        __builtin_amdgcn_global_load_lds(                                      \
            (const __attribute__((address_space(1))) unsigned int*)src_,       \
            (__attribute__((address_space(3))) unsigned int*)dst_, 16, 0, 0);  \
    }                                                                          \
} while (0)

    // ---- A fragments in registers: af[fm][ks] = 8 short8 = 32 VGPR ----
    short8 af[2][4];
    #pragma unroll
    for (int fm = 0; fm < 2; ++fm)
        #pragma unroll
        for (int ks = 0; ks < 4; ++ks)
            af[fm][ks] = *reinterpret_cast<const short8*>(
                Qb + (size_t)(qbase + wr + fm * 16 + lr) * DDIM + (ks * 4 + lk) * 8);

    float thrv[2][4];
    if (MODE == 1) {
        #pragma unroll
        for (int fm = 0; fm < 2; ++fm)
            #pragma unroll
            for (int j = 0; j < 4; ++j)
                thrv[fm][j] = thr[qbase + wr + fm * 16 + lk * 4 + j] - EPSM;
    }

    STAGE(0, t0, 0);
    __syncthreads();
    int cur = 0;

    for (int t = 0; t < tcnt; ++t) {
        const int cbase = (t0 + t) * 64;

        const f32x4 z = {0.f, 0.f, 0.f, 0.f};
        f32x4 acc[2][2];
        #pragma unroll
        for (int a = 0; a < 2; ++a)
            #pragma unroll
            for (int b = 0; b < 2; ++b) acc[a][b] = z;

        // ---------- half 0 (dims 0..63; af[.][0..1]) ----------
        STAGE(cur ^ 1, t0 + t, 1);                 // in flight under compute
        {
            const unsigned char* bsc = Bs[cur];
            #pragma unroll
            for (int ksl = 0; ksl < 2; ++ksl) {
                short8 bg[2];
                #pragma unroll
                for (int fn = 0; fn < 2; ++fn) {
                    int rb = wc + fn * 16 + lr;
                    bg[fn] = *reinterpret_cast<const short8*>(
                        bsc + rb * 128 + (((ksl * 4 + lk) ^ (rb & 7)) << 4));
                }
                #pragma unroll
                for (int fm = 0; fm < 2; ++fm)
                    #pragma unroll
                    for (int fn = 0; fn < 2; ++fn)
                        acc[fm][fn] = __builtin_amdgcn_mfma_f32_16x16x32_bf16(
                            af[fm][ksl], bg[fn], acc[fm][fn], 0, 0, 0);
            }
        }
        __syncthreads();
        cur ^= 1;

        // ---------- half 1 (dims 64..127; af[.][2..3]) ----------
        if (t + 1 < tcnt) STAGE(cur ^ 1, t0 + t + 1, 0);
        {
            const unsigned char* bsc = Bs[cur];
            #pragma unroll
            for (int ksl = 0; ksl < 2; ++ksl) {
                short8 bg[2];
                #pragma unroll
                for (int fn = 0; fn < 2; ++fn) {
                    int rb = wc + fn * 16 + lr;
                    bg[fn] = *reinterpret_cast<const short8*>(
                        bsc + rb * 128 + (((ksl * 4 + lk) ^ (rb & 7)) << 4));
                }
                #pragma unroll
                for (int fm = 0; fm < 2; ++fm)
                    #pragma unroll
                    for (int fn = 0; fn < 2; ++fn)
                        acc[fm][fn] = __builtin_amdgcn_mfma_f32_16x16x32_bf16(
                            af[fm][2 + ksl], bg[fn], acc[fm][fn], 0, 0, 0);
            }
        }

        // epilogue — C/D map: col = lane&15, row = (lane>>4)*4 + reg [m89/m91]
        #pragma unroll
        for (int fm = 0; fm < 2; ++fm) {
            #pragma unroll
            for (int j = 0; j < 4; ++j) {
                const int ql = wr + fm * 16 + lk * 4 + j;
                if (MODE == 0) {
                    #pragma unroll
                    for (int fn = 0; fn < 2; ++fn) {
                        const int c = cbase + wc + fn * 16 + lr;
                        float s = acc[fm][fn][j];
                        int b = (int)((s + 1.0f) * (NBINS * 0.5f));
                        b = b < 0 ? 0 : (b > NBINS - 1 ? NBINS - 1 : b);
                        binsU8[(size_t)(qbase + ql) * MSAMPLE + c] = (unsigned char)b;
                    }
                } else {
                    const float t_ = thrv[fm][j];
                    const float s0 = acc[fm][0][j], s1 = acc[fm][1][j];
                    if (__any(fmaxf(s0, s1) >= t_)) {
                        #pragma unroll
                        for (int fn = 0; fn < 2; ++fn) {
                            const int c = cbase + wc + fn * 16 + lr;
                            const float s = fn ? s1 : s0;
                            if (c < N && s >= t_) {
                                int qs = (int)((s + 1.0f) * 16384.0f);
                                qs = qs < 0 ? 0 : (qs > 32767 ? 32767 : qs);
                                unsigned key = ((unsigned)qs << QSH)
                                             | (~(unsigned)c & QMASK);
                                int p = atomicAdd(&off_l[ql], 1);   // LDS-local
                                if (p < BCAP)
                                    buckets[((size_t)(qbase + ql) * NGRP + g) * BCAP + p] = key;
                            }
                        }
                    }
                }
            }
        }
        __syncthreads();
        cur ^= 1;
    }
#undef STAGE

    if (MODE == 1) {
        for (int i = tid; i < 64; i += 256)
            cnt2[(qbase + i) * NGRP + g] = min(off_l[i], BCAP);
    }
}

// ---------------------------------------------------------------------------
// thresh with per-wave sub-histograms (identical to R12; bins over [-1,1])
// ---------------------------------------------------------------------------
__global__ __launch_bounds__(256)
void thresh_kernel(const unsigned char* __restrict__ bins, float* __restrict__ thr)
{
    __shared__ int hS[4 * NBINS];
    __shared__ int hA[NBINS];
    __shared__ int hB[NBINS];
    __shared__ int best;
    const int q = blockIdx.x, tid = threadIdx.x;
    const int wv = tid >> 6;
    for (int i = tid; i < 4 * NBINS; i += 256) hS[i] = 0;
    if (tid == 0) best = 0;
    __syncthreads();
    const uint4* bp = reinterpret_cast<const uint4*>(bins + (size_t)q * MSAMPLE);
    int* hw = hS + wv * NBINS;
    for (int i = tid; i < MSAMPLE / 16; i += 256) {
        uint4 v = bp[i];
        unsigned xs[4] = {v.x, v.y, v.z, v.w};
        #pragma unroll
        for (int k = 0; k < 4; ++k) {
            unsigned x = xs[k];
            atomicAdd(&hw[x & 255], 1); x >>= 8;
            atomicAdd(&hw[x & 255], 1); x >>= 8;
            atomicAdd(&hw[x & 255], 1); x >>= 8;
            atomicAdd(&hw[x & 255], 1);
        }
    }
    __syncthreads();
    for (int i = tid; i < NBINS; i += 256)
        hA[i] = hS[i] + hS[NBINS + i] + hS[2 * NBINS + i] + hS[3 * NBINS + i];
    __syncthreads();
    int* src = hA; int* dst = hB;
    for (int off = 1; off < NBINS; off <<= 1) {
        for (int i = tid; i < NBINS; i += 256)
            dst[i] = src[i] + ((i + off < NBINS) ? src[i + off] : 0);
        __syncthreads();
        int* tmp = src; src = dst; dst = tmp;
    }
    for (int i = tid; i < NBINS; i += 256)
        if (src[i] >= TOPK) atomicMax(&best, i);
    __syncthreads();
    if (tid == 0)
        thr[q] = (float)(best - 1) * (2.0f / NBINS) - 1.0f;
}

// ---------------------------------------------------------------------------
// Finalize (identical to R12): compact unsorted -> 256-bin histogram rank-
// selection -> exact fp32 rbf for head set -> 256-wide u64 bitonic
// (rbf desc, idx asc = jax.lax.top_k) -> weights, V/e gathers.
// ---------------------------------------------------------------------------
__global__ __launch_bounds__(256)
void finalize_kernel(const unsigned int* __restrict__ buckets, const int* __restrict__ cnt2,
                     const float* __restrict__ Qg, const float* __restrict__ Kg,
                     const float* __restrict__ V, const float* __restrict__ hIn,
                     const float* __restrict__ eIn,
                     float* __restrict__ out, int N)
{
    __shared__ float qv[DDIM];
    __shared__ unsigned sk[SORTN];
    __shared__ unsigned fk[FINEN];
    __shared__ unsigned long long sk64[FINEN];
    __shared__ int hA[NBINS];
    __shared__ int hB[NBINS];
    __shared__ int cnts[NGRP], offs[NGRP];
    __shared__ int wpart[2];
    __shared__ int bestb, nsel;
    __shared__ float selV[TOPK];
    __shared__ int   selI[TOPK];
    __shared__ float wts[TOPK];
    const int q = blockIdx.x, tid = threadIdx.x;

    if (tid < DDIM) qv[tid] = Qg[(size_t)q * DDIM + tid];
    if (tid < NGRP) cnts[tid] = cnt2[q * NGRP + tid];
    for (int i = tid; i < SORTN; i += 256) sk[i] = 0u;
    if (tid < NBINS) hA[tid] = 0;
    if (tid < FINEN) sk64[tid] = 0ull;
    if (tid == 0) { bestb = 0; nsel = 0; }
    __syncthreads();
    int cv = 0, xv = 0;
    if (tid < NGRP) {
        cv = cnts[tid];
        xv = cv;
        #pragma unroll
        for (int o = 1; o < 64; o <<= 1) {
            int y = __shfl_up(xv, o);
            if ((tid & 63) >= o) xv += y;
        }
        if ((tid & 63) == 63) wpart[tid >> 6] = xv;
    }
    __syncthreads();
    if (tid < NGRP) {
        int add = (tid >= 64) ? wpart[0] : 0;
        offs[tid] = xv - cv + add;
    }
    __syncthreads();
    for (int flat = tid; flat < NGRP * BCAP; flat += 256) {
        int gg = flat / BCAP, j = flat - gg * BCAP;
        if (j < cnts[gg]) {
            int dst = offs[gg] + j;
            if (dst < SORTN)
                sk[dst] = buckets[((size_t)q * NGRP + gg) * BCAP + j];
        }
    }
    __syncthreads();
    for (int i = tid; i < SORTN; i += 256) {
        unsigned k = sk[i];
        if (k) atomicAdd(&hA[k >> 24], 1);
    }
    __syncthreads();
    {
        int* src = hA; int* dst = hB;
        for (int off = 1; off < NBINS; off <<= 1) {
            for (int i = tid; i < NBINS; i += 256)
                dst[i] = src[i] + ((i + off < NBINS) ? src[i + off] : 0);
            __syncthreads();
            int* tmp = src; src = dst; dst = tmp;
        }
        for (int i = tid; i < NBINS; i += 256)
            if (src[i] >= TOPK) atomicMax(&bestb, i);
    }
    __syncthreads();
    const unsigned b32q = (unsigned)bestb << 7;
    const unsigned cutq = b32q > QMARGIN ? b32q - QMARGIN : 0u;
    const unsigned cutKey = cutq << QSH;
    for (int i = tid; i < SORTN; i += 256) {
        unsigned k = sk[i];
        if (k != 0u && k >= cutKey) {
            int p = atomicAdd(&nsel, 1);
            if (p < FINEN) fk[p] = k;
        }
    }
    __syncthreads();
    const int m = min(nsel, FINEN);
    const int sub = tid & 3, ci = tid >> 2;
    #pragma unroll
    for (int base = 0; base < FINEN; base += 64) {
        int i = base + ci;
        bool act = i < m;
        int c = 0;
        float s = 0.f;
        if (act) {
            c = (int)(~fk[i] & QMASK);
            const float4* k4 = reinterpret_cast<const float4*>(Kg + (size_t)c * DDIM) + sub;
            const float4* q4 = reinterpret_cast<const float4*>(qv) + sub;
            #pragma unroll
            for (int d = 0; d < 8; ++d) {
                float4 kk = k4[d * 4];
                float4 qq = q4[d * 4];
                s = fmaf(qq.x, kk.x, s); s = fmaf(qq.y, kk.y, s);
                s = fmaf(qq.z, kk.z, s); s = fmaf(qq.w, kk.w, s);
            }
        }
        s += __shfl_xor(s, 1); s += __shfl_xor(s, 2);
        if (act && sub == 0) {
            float dist = 2.0f - 2.0f * s;              // reference op order
            float rbf = expf(dist * -2.0f);            // exp(-dist/(2*0.25))
            sk64[i] = ((unsigned long long)__float_as_uint(rbf) << 32)
                    | (unsigned)(~(unsigned)c);        // rbf desc, then idx asc
        }
    }
    __syncthreads();
    for (int k = 2; k <= FINEN; k <<= 1) {
        for (int j = k >> 1; j > 0; j >>= 1) {
            int x = tid ^ j;
            if (x > tid) {
                unsigned long long a = sk64[tid], b = sk64[x];
                bool sw = ((tid & k) == 0) ? (a < b) : (a > b);
                if (sw) { sk64[tid] = b; sk64[x] = a; }
            }
            __syncthreads();
        }
    }
    if (tid < TOPK) {
        unsigned long long kk = sk64[tid];
        float rbf = __uint_as_float((unsigned)(kk >> 32));
        int   idx = (int)(~(unsigned)kk);
        selV[tid] = rbf; selI[tid] = idx;
        float lw = logf(rbf + 1e-8f) + logf(hIn[idx] + 1e-8f);
        float mx = lw;
        #pragma unroll
        for (int o = 16; o > 0; o >>= 1) mx = fmaxf(mx, __shfl_xor(mx, o));
        float ex = expf(lw - mx);
        float sm = ex;
        #pragma unroll
        for (int o = 16; o > 0; o >>= 1) sm += __shfl_xor(sm, o);
        wts[tid] = ex / sm;
    }
    __syncthreads();
    {
        float acc = 0.f;
        const int v = tid;
        #pragma unroll
        for (int k = 0; k < TOPK; ++k)
            acc = fmaf(wts[k], V[(size_t)selI[k] * 256 + v], acc);
        out[(size_t)q * 256 + v] = acc;
    }
    const int offE = NQTOT * 256;
    const int offW = offE + NQTOT * 4;
    const int offI = offW + NQTOT * TOPK;
    if (tid < 4) {
        float acc = 0.f;
        #pragma unroll
        for (int k = 0; k < TOPK; ++k)
            acc = fmaf(wts[k], eIn[(size_t)selI[k] * 4 + tid], acc);
        out[offE + q * 4 + tid] = acc;
    }
    if (tid < TOPK) {
        out[offW + q * TOPK + tid] = wts[tid];
        out[offI + q * TOPK + tid] = (float)selI[tid];
    }
}

// ---------------------------------------------------------------------------
extern "C" void kernel_launch(void* const* d_in, const int* in_sizes, int n_in,
                              void* d_out, int out_size, void* d_ws, size_t ws_size,
                              hipStream_t stream)
{
    (void)n_in; (void)out_size; (void)ws_size;
    const float* Qg = (const float*)d_in[0];
    const float* Kg = (const float*)d_in[1];
    const float* Vg = (const float*)d_in[2];
    const float* hg = (const float*)d_in[3];
    const float* eg = (const float*)d_in[4];
    const int N = in_sizes[1] / DDIM;          // 100000

    char* w = (char*)d_ws;
    unsigned short* Kbf = (unsigned short*)w;  w += (size_t)N * DDIM * 2;      // 25.6MB
    unsigned short* Qbf = (unsigned short*)w;  w += (size_t)NQTOT * DDIM * 2;  // 256KB
    float* thr = (float*)w;                    w += NQTOT * 4;                 // 4KB
    int*   cnt2 = (int*)w;                     w += (size_t)NQTOT * NGRP * 4;  // 512KB
    unsigned char* binsU8 = (unsigned char*)w;                                 // 12.58MB
    unsigned int*  buckets = (unsigned int*)w; // aliases binsU8 (sequential lifetimes)

    hipMemsetAsync(cnt2, 0, (size_t)NQTOT * NGRP * 4, stream);

    dim3 blk(256);
    convert_kernel<<<dim3(2048), blk, 0, stream>>>(
        Qg, Kg, Qbf, Kbf, NQTOT * DDIM / 8, N * DDIM / 8);
    gemm_pass<0><<<dim3(MSAMPLE / 64, NQTOT / 64), blk, 0, stream>>>(
        Qbf, Kbf, N, binsU8, nullptr, nullptr, nullptr);
    thresh_kernel<<<dim3(NQTOT), blk, 0, stream>>>(binsU8, thr);
    gemm_pass<1><<<dim3(NGRP, NQTOT / 64), blk, 0, stream>>>(
        Qbf, Kbf, N, nullptr, thr, cnt2, buckets);
    finalize_kernel<<<dim3(NQTOT), blk, 0, stream>>>(
        buckets, cnt2, Qg, Kg, Vg, hg, eg, (float*)d_out, N);
}